// Round 19
// baseline (586.738 us; speedup 1.0000x reference)
//
#include <hip/hip_runtime.h>
#include <hip/hip_bf16.h>
#include <math.h>

#define BB 64
#define LL 384
#define DD 128
#define HH 8
#define DHH 16
#define DEPTH 6
#define FFD 512
#define MROWS (BB*LL)      // 24576
#define COUT 128
#define KP (LL*DD)         // 49152
#define KSPLIT 96
#define KCHUNK 512

typedef short bf16x8 __attribute__((ext_vector_type(8)));
typedef float f32x4 __attribute__((ext_vector_type(4)));

__device__ __forceinline__ unsigned short f2bs(float x) {
    __hip_bfloat16 h = __float2bfloat16(x);
    return *reinterpret_cast<unsigned short*>(&h);
}
__device__ __forceinline__ float bs2f(unsigned short u) {
    unsigned int v = ((unsigned int)u) << 16;
    return __uint_as_float(v);
}
__device__ __forceinline__ float gelu_exact(float x) {
    return 0.5f * x * (1.0f + erff(x * 0.70710678118654752f));
}

// ---------------- embed + axial pos + layer-0 LN1 (fused) ----------------
__global__ __launch_bounds__(256) void embedln_kernel(
    const int* __restrict__ x_enc, const float* __restrict__ emb,
    const float* __restrict__ pos1, const float* __restrict__ pos2,
    const float* __restrict__ g, const float* __restrict__ b,
    float* __restrict__ x1, float* __restrict__ x2,
    __hip_bfloat16* __restrict__ y)
{
    int wave = threadIdx.x >> 6;
    int lane = threadIdx.x & 63;
    int row = blockIdx.x * 4 + wave;
    int l = row % LL;
    int tok = x_enc[row];
    float2 e  = ((const float2*)(emb + (size_t)tok * DD))[lane];
    float2 p1 = ((const float2*)(pos1 + (l / 25) * DD))[lane];
    float2 p2 = ((const float2*)(pos2 + (l % 25) * DD))[lane];
    float2 v = make_float2(e.x + p1.x + p2.x, e.y + p1.y + p2.y);
    ((float2*)(x1 + (size_t)row * DD))[lane] = v;
    ((float2*)(x2 + (size_t)row * DD))[lane] = v;
    float2 gg = ((const float2*)g)[lane];
    float2 bb = ((const float2*)b)[lane];
    float s = v.x + v.y;
    float sq = v.x * v.x + v.y * v.y;
    #pragma unroll
    for (int off = 32; off > 0; off >>= 1) {
        s += __shfl_down(s, off, 64);
        sq += __shfl_down(sq, off, 64);
    }
    s = __shfl(s, 0, 64);
    sq = __shfl(sq, 0, 64);
    float mean = s * (1.0f / DD);
    float var = sq * (1.0f / DD) - mean * mean;
    float rstd = rsqrtf(var + 1e-5f);
    __hip_bfloat16* yp = y + (size_t)row * DD + lane * 2;
    yp[0] = __float2bfloat16((v.x - mean) * rstd * gg.x + bb.x);
    yp[1] = __float2bfloat16((v.y - mean) * rstd * gg.y + bb.y);
}

// ---------------- weight cast + transpose ----------------
__device__ __forceinline__ void castT_body(
    const float* __restrict__ s, __hip_bfloat16* __restrict__ d,
    int K, int N, int kb, int nb)
{
    __shared__ float tile[32][33];
    int tx = threadIdx.x & 31, ty = threadIdx.x >> 5;
    #pragma unroll
    for (int r = 0; r < 32; r += 8)
        tile[r + ty][tx] = s[(size_t)(kb + r + ty) * N + nb + tx];
    __syncthreads();
    #pragma unroll
    for (int r = 0; r < 32; r += 8)
        d[(size_t)(nb + r + ty) * K + kb + tx] = __float2bfloat16(tile[tx][r + ty]);
}

__global__ __launch_bounds__(256) void cast_all_kernel(
    const float* __restrict__ Wqk, const float* __restrict__ Wv,
    const float* __restrict__ Wo,  const float* __restrict__ W1,
    const float* __restrict__ W2,
    __hip_bfloat16* __restrict__ dqk, __hip_bfloat16* __restrict__ dv,
    __hip_bfloat16* __restrict__ dwo, __hip_bfloat16* __restrict__ d1,
    __hip_bfloat16* __restrict__ d2)
{
    int z = blockIdx.x;
    if (z < 288) {
        int m = z >> 4, t = z & 15;
        int which = m / 6, dd = m % 6;
        const float* s = (which == 0 ? Wqk : (which == 1 ? Wv : Wo)) + (size_t)dd * 16384;
        __hip_bfloat16* d = (which == 0 ? dqk : (which == 1 ? dv : dwo))
                            + (size_t)dd * (which == 2 ? 16384 : 32768);
        castT_body(s, d, 128, 128, (t >> 2) * 32, (t & 3) * 32);
    } else if (z < 672) {
        int i = z - 288; int dd = i >> 6; int t = i & 63;
        castT_body(W1 + (size_t)dd * 65536, d1 + (size_t)dd * 65536,
                   128, 512, (t >> 4) * 32, (t & 15) * 32);
    } else {
        int i = z - 672; int dd = i >> 6; int t = i & 63;
        castT_body(W2 + (size_t)dd * 65536, d2 + (size_t)dd * 65536,
                   512, 128, (t >> 2) * 32, (t & 3) * 32);
    }
}

__global__ __launch_bounds__(256) void castWp_kernel(
    const float* __restrict__ src, __hip_bfloat16* __restrict__ dst)
{
    castT_body(src, dst, KP, 128, blockIdx.x * 32, blockIdx.y * 32);
}

// ---------------- bf16 MFMA GEMM (plain; layer-0 qkv) ----------------
template<int K, int N>
__global__ __launch_bounds__(256) void gemm_qkv_kernel(
    const __hip_bfloat16* __restrict__ A, const __hip_bfloat16* __restrict__ Bt,
    __hip_bfloat16* __restrict__ Cdst)
{
    __shared__ unsigned short As[64 * 128];
    __shared__ unsigned short Bs[128 * 128];
    int tid = threadIdx.x;
    int l = tid & 63, w = tid >> 6;
    int wr = w >> 1, wc = w & 1;
    int lr = l & 15, q = l >> 4;
    int m0 = blockIdx.y * 64;
    int n0 = blockIdx.x * 128;

    f32x4 acc[2][4];
    #pragma unroll
    for (int mt = 0; mt < 2; ++mt)
        #pragma unroll
        for (int nt = 0; nt < 4; ++nt) acc[mt][nt] = (f32x4){0.f, 0.f, 0.f, 0.f};

    for (int kt = 0; kt < K; kt += 128) {
        if (kt) __syncthreads();
        #pragma unroll
        for (int p = 0; p < 4; ++p) {
            int n = p * 256 + tid;
            int r = n >> 4;
            int c = (n & 15) ^ (r & 7);
            *(uint4*)&As[n * 8] = *(const uint4*)(A + (size_t)(m0 + r) * K + kt + c * 8);
        }
        #pragma unroll
        for (int p = 0; p < 8; ++p) {
            int n = p * 256 + tid;
            int r = n >> 4;
            int c = (n & 15) ^ (r & 7);
            *(uint4*)&Bs[n * 8] = *(const uint4*)(Bt + (size_t)(n0 + r) * K + kt + c * 8);
        }
        __syncthreads();
        #pragma unroll
        for (int kk = 0; kk < 4; ++kk) {
            bf16x8 afr[2], bfr[4];
            #pragma unroll
            for (int mt = 0; mt < 2; ++mt) {
                int rA = wr * 32 + mt * 16 + lr;
                int cc = (kk * 4 + q) ^ (rA & 7);
                afr[mt] = *(const bf16x8*)&As[(rA * 16 + cc) * 8];
            }
            #pragma unroll
            for (int nt = 0; nt < 4; ++nt) {
                int rB = wc * 64 + nt * 16 + lr;
                int cc = (kk * 4 + q) ^ (rB & 7);
                bfr[nt] = *(const bf16x8*)&Bs[(rB * 16 + cc) * 8];
            }
            #pragma unroll
            for (int mt = 0; mt < 2; ++mt)
                #pragma unroll
                for (int nt = 0; nt < 4; ++nt)
                    acc[mt][nt] = __builtin_amdgcn_mfma_f32_16x16x32_bf16(
                        afr[mt], bfr[nt], acc[mt][nt], 0, 0, 0);
        }
    }

    #pragma unroll
    for (int mt = 0; mt < 2; ++mt)
        #pragma unroll
        for (int nt = 0; nt < 4; ++nt) {
            int col = n0 + wc * 64 + nt * 16 + lr;
            #pragma unroll
            for (int r = 0; r < 4; ++r) {
                int row = m0 + wr * 32 + mt * 16 + q * 4 + r;
                Cdst[(size_t)row * N + col] = __float2bfloat16(acc[mt][nt][r]);
            }
        }
}

// ---------------- attention: MFMA flash-style, S^T, 2 blocks per (b,h) (r16-verified) ----------------
__global__ __launch_bounds__(256) void attn_kernel(
    const __hip_bfloat16* __restrict__ qkv, __hip_bfloat16* __restrict__ o)
{
    int z  = blockIdx.x >> 9;
    int bh = blockIdx.x & 511;
    int b = bh >> 3, hh = bh & 7;
    const unsigned short* base = (const unsigned short*)qkv + (size_t)b * LL * 256 + hh * DHH;

    __shared__ unsigned short knb[LL + 2][24];
    __shared__ unsigned short vtb[16][LL + 24];
    __shared__ float cq[LL];
    __shared__ unsigned short ptile[4][16][40];

    int t = threadIdx.x;
    for (int r = t; r < LL; r += 256) {
        const unsigned short* qp = base + (size_t)r * 256;
        unsigned short qs[16], vs16[16];
        *(uint4*)&qs[0]  = *(const uint4*)(qp);
        *(uint4*)&qs[8]  = *(const uint4*)(qp + 8);
        *(uint4*)&vs16[0] = *(const uint4*)(qp + 128);
        *(uint4*)&vs16[8] = *(const uint4*)(qp + 136);
        float q[16];
        #pragma unroll
        for (int d = 0; d < 16; ++d) q[d] = bs2f(qs[d]);
        float nrm = 0.f;
        #pragma unroll
        for (int d = 0; d < 16; ++d) nrm = fmaf(q[d], q[d], nrm);
        float qn = sqrtf(nrm);
        float inv = 1.0f / fmaxf(qn, 1e-12f);
        cq[r] = 0.25f * qn;
        unsigned short kb[16];
        #pragma unroll
        for (int d = 0; d < 16; ++d) kb[d] = f2bs(q[d] * inv);
        *(uint4*)&knb[r][0] = *(uint4*)&kb[0];
        *(uint4*)&knb[r][8] = *(uint4*)&kb[8];
        *(uint4*)&knb[r][16] = make_uint4(0u, 0u, 0u, 0u);
        #pragma unroll
        for (int d = 0; d < 16; ++d) vtb[d][r] = vs16[d];
    }
    if (t < 16) {
        #pragma unroll
        for (int c = 0; c < 24; ++c) vtb[t][LL + c] = 0;
    }
    if (t < 2) {
        #pragma unroll
        for (int c = 0; c < 24; ++c) knb[LL + t][c] = 0;
    }

    int w = t >> 6, l = t & 63;
    int lr = l & 15, q4 = l >> 4;
    __syncthreads();

    bf16x8 zfrag = {0, 0, 0, 0, 0, 0, 0, 0};
    bf16x8 onesf;
    #pragma unroll
    for (int i = 0; i < 8; ++i) onesf[i] = (short)0x3F80;

    int slot = 2 * w + z;
    int strips[3] = { slot, 15 - slot, 16 + slot };
    #pragma unroll
    for (int si = 0; si < 3; ++si) {
        int s = strips[si];
        int r0 = s * 16;
        bf16x8 bq = *(const bf16x8*)&knb[r0 + lr][q4 * 8];
        float ccq = cq[r0 + lr];
        int qg = r0 + lr;

        f32x4 oacc = (f32x4){0.f, 0.f, 0.f, 0.f};
        f32x4 lacc = (f32x4){0.f, 0.f, 0.f, 0.f};

        for (int jt = 0; jt <= s; jt += 2) {
            bf16x8 a0 = *(const bf16x8*)&knb[jt * 16 + lr][(q4 & 1) * 8];
            a0 = (q4 < 2) ? a0 : zfrag;
            bf16x8 a1 = *(const bf16x8*)&knb[(jt + 1) * 16 + lr][(q4 & 1) * 8];
            a1 = (q4 < 2) ? a1 : zfrag;
            f32x4 s0 = __builtin_amdgcn_mfma_f32_16x16x32_bf16(
                a0, bq, (f32x4){0.f, 0.f, 0.f, 0.f}, 0, 0, 0);
            f32x4 s1 = __builtin_amdgcn_mfma_f32_16x16x32_bf16(
                a1, bq, (f32x4){0.f, 0.f, 0.f, 0.f}, 0, 0, 0);

            unsigned int pk0[2], pk1[2];
            #pragma unroll
            for (int h = 0; h < 2; ++h) {
                int ja = jt * 16 + q4 * 4 + 2 * h;
                float pa = __expf(fmaf(s0[2 * h],     ccq, -ccq));
                pa = (ja < qg) ? pa : 0.f;
                float pb = __expf(fmaf(s0[2 * h + 1], ccq, -ccq));
                pb = (ja + 1 < qg) ? pb : 0.f;
                pk0[h] = (unsigned int)f2bs(pa) | ((unsigned int)f2bs(pb) << 16);
                float pc = __expf(fmaf(s1[2 * h],     ccq, -ccq));
                pc = (ja + 16 < qg) ? pc : 0.f;
                float pd = __expf(fmaf(s1[2 * h + 1], ccq, -ccq));
                pd = (ja + 17 < qg) ? pd : 0.f;
                pk1[h] = (unsigned int)f2bs(pc) | ((unsigned int)f2bs(pd) << 16);
            }
            *(uint2*)&ptile[w][lr][q4 * 4]      = make_uint2(pk0[0], pk0[1]);
            *(uint2*)&ptile[w][lr][16 + q4 * 4] = make_uint2(pk1[0], pk1[1]);
            asm volatile("s_waitcnt lgkmcnt(0)" ::: "memory");
            bf16x8 pfrag = *(const bf16x8*)&ptile[w][lr][q4 * 8];
            bf16x8 vfrag = *(const bf16x8*)&vtb[lr][jt * 16 + q4 * 8];
            oacc = __builtin_amdgcn_mfma_f32_16x16x32_bf16(pfrag, vfrag, oacc, 0, 0, 0);
            lacc = __builtin_amdgcn_mfma_f32_16x16x32_bf16(pfrag, onesf, lacc, 0, 0, 0);
        }

        if (s == 0 && q4 == 0) {
            lacc[0] = 1.0f;
            oacc[0] = bs2f(vtb[lr][0]);
        }
        unsigned short* ob = (unsigned short*)o + (size_t)(b * LL + r0) * DD + hh * 16 + lr;
        #pragma unroll
        for (int reg = 0; reg < 4; ++reg) {
            float ov = oacc[reg] / lacc[reg];
            ob[(size_t)(q4 * 4 + reg) * DD] = f2bs(ov);
        }
    }
}

// ---------------- mega_layer (BM=32): wo+LN2+ff1/ff2-interleaved(hff in LDS)+LN1'+qkv ----------------
// r14 structure re-run at the r16 operating point: 48 KB LDS -> 3 blocks/CU, grid 768.
// LAST: final avg-LN with x1, h->hout, no x2 write, no qkv.
template<bool LAST>
__global__ __launch_bounds__(256) void mega_layer_kernel(
    const __hip_bfloat16* __restrict__ Ao, const __hip_bfloat16* __restrict__ WoTd,
    const float* __restrict__ bod, float* __restrict__ x1,
    const float* __restrict__ ln2g, const float* __restrict__ ln2b,
    const __hip_bfloat16* __restrict__ W1Td, const float* __restrict__ b1d,
    const __hip_bfloat16* __restrict__ W2Td, const float* __restrict__ b2d,
    float* __restrict__ x2,
    const float* __restrict__ ln1g, const float* __restrict__ ln1b,
    const __hip_bfloat16* __restrict__ WqvTd, __hip_bfloat16* __restrict__ qkv,
    __hip_bfloat16* __restrict__ hout)
{
    __shared__ unsigned short As[32 * 128];    // o tile -> hff chunk (A-layout swizzled)
    __shared__ unsigned short Bs[128 * 128];   // weights / fp32 LN tile (16 KB used)
    __shared__ unsigned short Hs[32 * 128];    // h tile (A-layout swizzled)
    int tid = threadIdx.x;
    int l = tid & 63, w = tid >> 6;
    int lr = l & 15, q = l >> 4;
    int m0 = blockIdx.x * 32;

    // ---- phase 1: o @ WoT (K=128) ----
    f32x4 acc[2][2];
    #pragma unroll
    for (int mt = 0; mt < 2; ++mt)
        #pragma unroll
        for (int nt = 0; nt < 2; ++nt) acc[mt][nt] = (f32x4){0.f, 0.f, 0.f, 0.f};

    #pragma unroll
    for (int p = 0; p < 2; ++p) {
        int n = p * 256 + tid;
        int r = n >> 4;
        int c = (n & 15) ^ (r & 7);
        *(uint4*)&As[n * 8] = *(const uint4*)(Ao + (size_t)(m0 + r) * 128 + c * 8);
    }
    #pragma unroll
    for (int p = 0; p < 8; ++p) {
        int n = p * 256 + tid;
        int r = n >> 4;
        int c = (n & 15) ^ (r & 7);
        *(uint4*)&Bs[n * 8] = *(const uint4*)(WoTd + (size_t)r * 128 + c * 8);
    }
    __syncthreads();
    #pragma unroll
    for (int kk = 0; kk < 4; ++kk) {
        bf16x8 afr[2], bfr[2];
        #pragma unroll
        for (int mt = 0; mt < 2; ++mt) {
            int rA = mt * 16 + lr;
            int cc = (kk * 4 + q) ^ (rA & 7);
            afr[mt] = *(const bf16x8*)&As[(rA * 16 + cc) * 8];
        }
        #pragma unroll
        for (int nt = 0; nt < 2; ++nt) {
            int rB = w * 32 + nt * 16 + lr;
            int cc = (kk * 4 + q) ^ (rB & 7);
            bfr[nt] = *(const bf16x8*)&Bs[(rB * 16 + cc) * 8];
        }
        #pragma unroll
        for (int mt = 0; mt < 2; ++mt)
            #pragma unroll
            for (int nt = 0; nt < 2; ++nt)
                acc[mt][nt] = __builtin_amdgcn_mfma_f32_16x16x32_bf16(
                    afr[mt], bfr[nt], acc[mt][nt], 0, 0, 0);
    }

    // ---- LN2 epilogue: fp32 tile in Bs, x1 residual out, h -> Hs ----
    float* fp = (float*)Bs;
    __syncthreads();
    #pragma unroll
    for (int mt = 0; mt < 2; ++mt)
        #pragma unroll
        for (int nt = 0; nt < 2; ++nt) {
            int col = w * 32 + nt * 16 + lr;
            float bv = bod[col];
            #pragma unroll
            for (int r = 0; r < 4; ++r) {
                int rowL = mt * 16 + q * 4 + r;
                fp[rowL * 128 + col] = acc[mt][nt][r] + bv
                                       + x1[(size_t)(m0 + rowL) * 128 + col];
            }
        }
    __syncthreads();
    {
        int rl = tid >> 3, sub = tid & 7;
        float s = 0.f, sq = 0.f;
        #pragma unroll
        for (int c4 = 0; c4 < 4; ++c4) {
            float4 v = *(const float4*)&fp[rl * 128 + sub * 16 + c4 * 4];
            s  += (v.x + v.y) + (v.z + v.w);
            sq += (v.x * v.x + v.y * v.y) + (v.z * v.z + v.w * v.w);
        }
        s  += __shfl_xor(s, 1);  s  += __shfl_xor(s, 2);  s  += __shfl_xor(s, 4);
        sq += __shfl_xor(sq, 1); sq += __shfl_xor(sq, 2); sq += __shfl_xor(sq, 4);
        float mean = s * (1.0f / 128.0f);
        float var  = sq * (1.0f / 128.0f) - mean * mean;
        float rstd = rsqrtf(var + 1e-5f);
        #pragma unroll
        for (int c4 = 0; c4 < 4; ++c4) {
            int col = sub * 16 + c4 * 4;
            float4 v  = *(const float4*)&fp[rl * 128 + col];
            *(float4*)(x1 + (size_t)(m0 + rl) * 128 + col) = v;
            float4 g4 = *(const float4*)(ln2g + col);
            float4 b4 = *(const float4*)(ln2b + col);
            unsigned short pk[4];
            pk[0] = f2bs((v.x - mean) * rstd * g4.x + b4.x);
            pk[1] = f2bs((v.y - mean) * rstd * g4.y + b4.y);
            pk[2] = f2bs((v.z - mean) * rstd * g4.z + b4.z);
            pk[3] = f2bs((v.w - mean) * rstd * g4.w + b4.w);
            int addr = rl * 128 + (((col >> 3) ^ (rl & 7)) << 3) + (col & 7);
            *(ushort4*)&Hs[addr] = *(ushort4*)&pk[0];
        }
    }
    __syncthreads();

    // ---- phase 2: ff1/ff2 interleaved; hff chunk lives in As (never global) ----
    f32x4 ffacc[2][2];
    #pragma unroll
    for (int mt = 0; mt < 2; ++mt)
        #pragma unroll
        for (int nt = 0; nt < 2; ++nt) ffacc[mt][nt] = (f32x4){0.f, 0.f, 0.f, 0.f};

    for (int nc = 0; nc < 4; ++nc) {
        if (nc) __syncthreads();   // fences prior iter's As/Bs reads
        #pragma unroll
        for (int p = 0; p < 8; ++p) {
            int n = p * 256 + tid;
            int r = n >> 4;
            int c = (n & 15) ^ (r & 7);
            *(uint4*)&Bs[n * 8] = *(const uint4*)(W1Td + (size_t)(nc * 128 + r) * 128 + c * 8);
        }
        __syncthreads();
        f32x4 a1[2][2];
        #pragma unroll
        for (int mt = 0; mt < 2; ++mt)
            #pragma unroll
            for (int nt = 0; nt < 2; ++nt) a1[mt][nt] = (f32x4){0.f, 0.f, 0.f, 0.f};
        #pragma unroll
        for (int kk = 0; kk < 4; ++kk) {
            bf16x8 afr[2], bfr[2];
            #pragma unroll
            for (int mt = 0; mt < 2; ++mt) {
                int rA = mt * 16 + lr;
                int cc = (kk * 4 + q) ^ (rA & 7);
                afr[mt] = *(const bf16x8*)&Hs[(rA * 16 + cc) * 8];
            }
            #pragma unroll
            for (int nt = 0; nt < 2; ++nt) {
                int rB = w * 32 + nt * 16 + lr;
                int cc = (kk * 4 + q) ^ (rB & 7);
                bfr[nt] = *(const bf16x8*)&Bs[(rB * 16 + cc) * 8];
            }
            #pragma unroll
            for (int mt = 0; mt < 2; ++mt)
                #pragma unroll
                for (int nt = 0; nt < 2; ++nt)
                    a1[mt][nt] = __builtin_amdgcn_mfma_f32_16x16x32_bf16(
                        afr[mt], bfr[nt], a1[mt][nt], 0, 0, 0);
        }
        // gelu -> hff chunk into As (A-layout swizzle; k = output col within chunk)
        #pragma unroll
        for (int mt = 0; mt < 2; ++mt)
            #pragma unroll
            for (int nt = 0; nt < 2; ++nt) {
                int k = w * 32 + nt * 16 + lr;
                float bv = b1d[nc * 128 + k];
                #pragma unroll
                for (int r = 0; r < 4; ++r) {
                    int row = mt * 16 + q * 4 + r;
                    int addr = row * 128 + (((k >> 3) ^ (row & 7)) << 3) + (k & 7);
                    As[addr] = f2bs(gelu_exact(a1[mt][nt][r] + bv));
                }
            }
        __syncthreads();   // hff complete; all waves done with Bs(W1)
        #pragma unroll
        for (int p = 0; p < 8; ++p) {
            int n = p * 256 + tid;
            int r = n >> 4;
            int c = (n & 15) ^ (r & 7);
            *(uint4*)&Bs[n * 8] = *(const uint4*)(W2Td + (size_t)r * 512 + nc * 128 + c * 8);
        }
        __syncthreads();
        #pragma unroll
        for (int kk = 0; kk < 4; ++kk) {
            bf16x8 afr[2], bfr[2];
            #pragma unroll
            for (int mt = 0; mt < 2; ++mt) {
                int rA = mt * 16 + lr;
                int cc = (kk * 4 + q) ^ (rA & 7);
                afr[mt] = *(const bf16x8*)&As[(rA * 16 + cc) * 8];
            }
            #pragma unroll
            for (int nt = 0; nt < 2; ++nt) {
                int rB = w * 32 + nt * 16 + lr;
                int cc = (kk * 4 + q) ^ (rB & 7);
                bfr[nt] = *(const bf16x8*)&Bs[(rB * 16 + cc) * 8];
            }
            #pragma unroll
            for (int mt = 0; mt < 2; ++mt)
                #pragma unroll
                for (int nt = 0; nt < 2; ++nt)
                    ffacc[mt][nt] = __builtin_amdgcn_mfma_f32_16x16x32_bf16(
                        afr[mt], bfr[nt], ffacc[mt][nt], 0, 0, 0);
        }
    }

    // ---- LN1'/avg-LN epilogue ----
    __syncthreads();
    #pragma unroll
    for (int mt = 0; mt < 2; ++mt)
        #pragma unroll
        for (int nt = 0; nt < 2; ++nt) {
            int col = w * 32 + nt * 16 + lr;
            float bv = b2d[col];
            #pragma unroll
            for (int r = 0; r < 4; ++r) {
                int rowL = mt * 16 + q * 4 + r;
                fp[rowL * 128 + col] = ffacc[mt][nt][r] + bv
                                       + x2[(size_t)(m0 + rowL) * 128 + col];
            }
        }
    __syncthreads();
    {
        int rl = tid >> 3, sub = tid & 7;
        float s = 0.f, sq = 0.f;
        #pragma unroll
        for (int c4 = 0; c4 < 4; ++c4) {
            float4 v = *(const float4*)&fp[rl * 128 + sub * 16 + c4 * 4];
            if (LAST) {
                float4 xo = *(const float4*)(x1 + (size_t)(m0 + rl) * 128 + sub * 16 + c4 * 4);
                v.x = (v.x + xo.x) * 0.5f; v.y = (v.y + xo.y) * 0.5f;
                v.z = (v.z + xo.z) * 0.5f; v.w = (v.w + xo.w) * 0.5f;
            }
            s  += (v.x + v.y) + (v.z + v.w);
            sq += (v.x * v.x + v.y * v.y) + (v.z * v.z + v.w * v.w);
        }
        s  += __shfl_xor(s, 1);  s  += __shfl_xor(s, 2);  s  += __shfl_xor(s, 4);
        sq += __shfl_xor(sq, 1); sq += __shfl_xor(sq, 2); sq += __shfl_xor(sq, 4);
        float mean = s * (1.0f / 128.0f);
        float var  = sq * (1.0f / 128.0f) - mean * mean;
        float rstd = rsqrtf(var + 1e-5f);
        #pragma unroll
        for (int c4 = 0; c4 < 4; ++c4) {
            int col = sub * 16 + c4 * 4;
            float4 v = *(const float4*)&fp[rl * 128 + col];
            if (LAST) {
                float4 xo = *(const float4*)(x1 + (size_t)(m0 + rl) * 128 + col);
                v.x = (v.x + xo.x) * 0.5f; v.y = (v.y + xo.y) * 0.5f;
                v.z = (v.z + xo.z) * 0.5f; v.w = (v.w + xo.w) * 0.5f;
            } else {
                *(float4*)(x2 + (size_t)(m0 + rl) * 128 + col) = v;
            }
            float4 g4 = *(const float4*)(ln1g + col);
            float4 b4 = *(const float4*)(ln1b + col);
            unsigned short pk[4];
            pk[0] = f2bs((v.x - mean) * rstd * g4.x + b4.x);
            pk[1] = f2bs((v.y - mean) * rstd * g4.y + b4.y);
            pk[2] = f2bs((v.z - mean) * rstd * g4.z + b4.z);
            pk[3] = f2bs((v.w - mean) * rstd * g4.w + b4.w);
            if (LAST) {
                *(ushort4*)((unsigned short*)hout + (size_t)(m0 + rl) * 128 + col)
                    = *(ushort4*)&pk[0];
            } else {
                int addr = rl * 128 + (((col >> 3) ^ (rl & 7)) << 3) + (col & 7);
                *(ushort4*)&Hs[addr] = *(ushort4*)&pk[0];
            }
        }
    }
    __syncthreads();

    // ---- phase 3: qkv = h @ WqvT (N=256, 2 chunks) ----
    if (!LAST) {
        for (int nc = 0; nc < 2; ++nc) {
            if (nc) __syncthreads();
            #pragma unroll
            for (int p = 0; p < 8; ++p) {
                int n = p * 256 + tid;
                int r = n >> 4;
                int c = (n & 15) ^ (r & 7);
                *(uint4*)&Bs[n * 8] = *(const uint4*)(WqvTd + (size_t)(nc * 128 + r) * 128 + c * 8);
            }
            __syncthreads();
            f32x4 a2[2][2];
            #pragma unroll
            for (int mt = 0; mt < 2; ++mt)
                #pragma unroll
                for (int nt = 0; nt < 2; ++nt) a2[mt][nt] = (f32x4){0.f, 0.f, 0.f, 0.f};
            #pragma unroll
            for (int kk = 0; kk < 4; ++kk) {
                bf16x8 afr[2], bfr[2];
                #pragma unroll
                for (int mt = 0; mt < 2; ++mt) {
                    int rA = mt * 16 + lr;
                    int cc = (kk * 4 + q) ^ (rA & 7);
                    afr[mt] = *(const bf16x8*)&Hs[(rA * 16 + cc) * 8];
                }
                #pragma unroll
                for (int nt = 0; nt < 2; ++nt) {
                    int rB = w * 32 + nt * 16 + lr;
                    int cc = (kk * 4 + q) ^ (rB & 7);
                    bfr[nt] = *(const bf16x8*)&Bs[(rB * 16 + cc) * 8];
                }
                #pragma unroll
                for (int mt = 0; mt < 2; ++mt)
                    #pragma unroll
                    for (int nt = 0; nt < 2; ++nt)
                        a2[mt][nt] = __builtin_amdgcn_mfma_f32_16x16x32_bf16(
                            afr[mt], bfr[nt], a2[mt][nt], 0, 0, 0);
            }
            #pragma unroll
            for (int mt = 0; mt < 2; ++mt)
                #pragma unroll
                for (int nt = 0; nt < 2; ++nt) {
                    int colg = nc * 128 + w * 32 + nt * 16 + lr;
                    #pragma unroll
                    for (int r = 0; r < 4; ++r) {
                        int row = m0 + mt * 16 + q * 4 + r;
                        qkv[(size_t)row * 256 + colg] = __float2bfloat16(a2[mt][nt][r]);
                    }
                }
        }
    }
}

// ---------------- final projection: MFMA split-K + reduce ----------------
__global__ __launch_bounds__(256) void final_mfma_kernel(
    const __hip_bfloat16* __restrict__ A, const __hip_bfloat16* __restrict__ Bt,
    float* __restrict__ partials)
{
    __shared__ unsigned short As[64 * 128];
    __shared__ unsigned short Bs[128 * 128];
    int tid = threadIdx.x;
    int l = tid & 63, w = tid >> 6;
    int wr = w >> 1, wc = w & 1;
    int lr = l & 15, q = l >> 4;
    int kbase = blockIdx.x * KCHUNK;

    f32x4 acc[2][4];
    #pragma unroll
    for (int mt = 0; mt < 2; ++mt)
        #pragma unroll
        for (int nt = 0; nt < 4; ++nt) acc[mt][nt] = (f32x4){0.f, 0.f, 0.f, 0.f};

    for (int kt = 0; kt < KCHUNK; kt += 128) {
        if (kt) __syncthreads();
        #pragma unroll
        for (int p = 0; p < 4; ++p) {
            int n = p * 256 + tid;
            int r = n >> 4;
            int c = (n & 15) ^ (r & 7);
            *(uint4*)&As[n * 8] = *(const uint4*)(A + (size_t)r * KP + kbase + kt + c * 8);
        }
        #pragma unroll
        for (int p = 0; p < 8; ++p) {
            int n = p * 256 + tid;
            int r = n >> 4;
            int c = (n & 15) ^ (r & 7);
            *(uint4*)&Bs[n * 8] = *(const uint4*)(Bt + (size_t)r * KP + kbase + kt + c * 8);
        }
        __syncthreads();
        #pragma unroll
        for (int kk = 0; kk < 4; ++kk) {
            bf16x8 afr[2], bfr[4];
            #pragma unroll
            for (int mt = 0; mt < 2; ++mt) {
                int rA = wr * 32 + mt * 16 + lr;
                int cc = (kk * 4 + q) ^ (rA & 7);
                afr[mt] = *(const bf16x8*)&As[(rA * 16 + cc) * 8];
            }
            #pragma unroll
            for (int nt = 0; nt < 4; ++nt) {
                int rB = wc * 64 + nt * 16 + lr;
                int cc = (kk * 4 + q) ^ (rB & 7);
                bfr[nt] = *(const bf16x8*)&Bs[(rB * 16 + cc) * 8];
            }
            #pragma unroll
            for (int mt = 0; mt < 2; ++mt)
                #pragma unroll
                for (int nt = 0; nt < 4; ++nt)
                    acc[mt][nt] = __builtin_amdgcn_mfma_f32_16x16x32_bf16(
                        afr[mt], bfr[nt], acc[mt][nt], 0, 0, 0);
        }
    }

    float* dst = partials + (size_t)blockIdx.x * (64 * 128);
    #pragma unroll
    for (int mt = 0; mt < 2; ++mt)
        #pragma unroll
        for (int nt = 0; nt < 4; ++nt) {
            int col = wc * 64 + nt * 16 + lr;
            #pragma unroll
            for (int r = 0; r < 4; ++r) {
                int row = wr * 32 + mt * 16 + q * 4 + r;
                dst[row * 128 + col] = acc[mt][nt][r];
            }
        }
}

__global__ __launch_bounds__(256) void final_reduce_kernel(
    const float* __restrict__ partials, const float* __restrict__ bp,
    float* __restrict__ out)
{
    int j = blockIdx.x * 256 + threadIdx.x;
    float s = bp[j & (COUT - 1)];
    #pragma unroll 8
    for (int p = 0; p < KSPLIT; ++p)
        s += partials[(size_t)p * 8192 + j];
    out[j] = s;
}

// ---------------- launch ----------------
extern "C" void kernel_launch(void* const* d_in, const int* in_sizes, int n_in,
                              void* d_out, int out_size, void* d_ws, size_t ws_size,
                              hipStream_t stream)
{
    const int*   x_enc = (const int*)  d_in[0];
    const float* emb   = (const float*)d_in[1];
    const float* pos1  = (const float*)d_in[2];
    const float* pos2  = (const float*)d_in[3];
    const float* ln1_g = (const float*)d_in[4];
    const float* ln1_b = (const float*)d_in[5];
    const float* Wqk   = (const float*)d_in[6];
    const float* Wv    = (const float*)d_in[7];
    const float* Wo    = (const float*)d_in[8];
    const float* bo    = (const float*)d_in[9];
    const float* ln2_g = (const float*)d_in[10];
    const float* ln2_b = (const float*)d_in[11];
    const float* W1    = (const float*)d_in[12];
    const float* b1    = (const float*)d_in[13];
    const float* W2    = (const float*)d_in[14];
    const float* b2    = (const float*)d_in[15];
    const float* lnf_g = (const float*)d_in[16];
    const float* lnf_b = (const float*)d_in[17];
    const float* Wp    = (const float*)d_in[18];
    const float* bp    = (const float*)d_in[19];
    float* out = (float*)d_out;

    const size_t SZ = (size_t)MROWS * DD;
    float* ws_f = (float*)d_ws;
    float* x1 = ws_f;                                        // fp32 [M,128]
    float* x2 = ws_f + SZ;                                   // fp32 [M,128]
    __hip_bfloat16* h_bf = (__hip_bfloat16*)(ws_f + 2 * SZ); // bf16 [M,128]
    __hip_bfloat16* o_bf = h_bf + SZ;                        // bf16 [M,128]
    __hip_bfloat16* wqvT = o_bf + SZ;                        // 6*[256,128]
    __hip_bfloat16* woT  = wqvT + 6 * 32768;                 // 6*[128,128]
    __hip_bfloat16* w1T  = woT  + 6 * 16384;                 // 6*[512,128]
    __hip_bfloat16* w2T  = w1T  + 6 * 65536;                 // 6*[128,512]
    __hip_bfloat16* WpT  = w2T  + 6 * 65536;                 // [128,49152] bf16
    __hip_bfloat16* qkv  = WpT;                              // [M,256] bf16 — ALIASES WpT
    float* partials = (float*)(WpT + (size_t)COUT * KP);     // [96][8192] fp32

    cast_all_kernel<<<dim3(1056), dim3(256), 0, stream>>>(
        Wqk, Wv, Wo, W1, W2, wqvT, wqvT + 16384, woT, w1T, w2T);
    embedln_kernel<<<dim3(MROWS / 4), dim3(256), 0, stream>>>(
        x_enc, emb, pos1, pos2, ln1_g, ln1_b, x1, x2, h_bf);
    gemm_qkv_kernel<128, 256><<<dim3(2, MROWS / 64), dim3(256), 0, stream>>>(
        h_bf, wqvT, qkv);

    for (int d = 0; d < DEPTH; ++d) {
        attn_kernel<<<dim3(BB * HH * 2), dim3(256), 0, stream>>>(qkv, o_bf);
        if (d < DEPTH - 1) {
            mega_layer_kernel<false><<<dim3(MROWS / 32), dim3(256), 0, stream>>>(
                o_bf, woT + (size_t)d * 16384, bo + d * DD, x1,
                ln2_g + d * DD, ln2_b + d * DD,
                w1T + (size_t)d * 65536, b1 + d * FFD,
                w2T + (size_t)d * 65536, b2 + d * DD, x2,
                ln1_g + (d + 1) * DD, ln1_b + (d + 1) * DD,
                wqvT + (size_t)(d + 1) * 32768, qkv, nullptr);
        } else {
            mega_layer_kernel<true><<<dim3(MROWS / 32), dim3(256), 0, stream>>>(
                o_bf, woT + (size_t)d * 16384, bo + d * DD, x1,
                ln2_g + d * DD, ln2_b + d * DD,
                w1T + (size_t)d * 65536, b1 + d * FFD,
                w2T + (size_t)d * 65536, b2 + d * DD, x2,
                lnf_g, lnf_b, nullptr, nullptr, h_bf);
        }
    }

    castWp_kernel<<<dim3(KP / 32, 4), dim3(256), 0, stream>>>(Wp, WpT);
    final_mfma_kernel<<<dim3(KSPLIT), dim3(256), 0, stream>>>(h_bf, WpT, partials);
    final_reduce_kernel<<<dim3(32), dim3(256), 0, stream>>>(partials, bp, out);
}

// Round 20
// 552.243 us; speedup vs baseline: 1.0625x; 1.0625x over previous
//
#include <hip/hip_runtime.h>
#include <hip/hip_bf16.h>
#include <math.h>

#define BB 64
#define LL 384
#define DD 128
#define HH 8
#define DHH 16
#define DEPTH 6
#define FFD 512
#define MROWS (BB*LL)      // 24576
#define COUT 128
#define KP (LL*DD)         // 49152
#define KSPLIT 96
#define KCHUNK 512

typedef short bf16x8 __attribute__((ext_vector_type(8)));
typedef float f32x4 __attribute__((ext_vector_type(4)));

__device__ __forceinline__ unsigned short f2bs(float x) {
    __hip_bfloat16 h = __float2bfloat16(x);
    return *reinterpret_cast<unsigned short*>(&h);
}
__device__ __forceinline__ float bs2f(unsigned short u) {
    unsigned int v = ((unsigned int)u) << 16;
    return __uint_as_float(v);
}
__device__ __forceinline__ float gelu_exact(float x) {
    return 0.5f * x * (1.0f + erff(x * 0.70710678118654752f));
}

// ---------------- embed + axial pos + layer-0 LN1 (fused) ----------------
__global__ __launch_bounds__(256) void embedln_kernel(
    const int* __restrict__ x_enc, const float* __restrict__ emb,
    const float* __restrict__ pos1, const float* __restrict__ pos2,
    const float* __restrict__ g, const float* __restrict__ b,
    float* __restrict__ x1, float* __restrict__ x2,
    __hip_bfloat16* __restrict__ y)
{
    int wave = threadIdx.x >> 6;
    int lane = threadIdx.x & 63;
    int row = blockIdx.x * 4 + wave;
    int l = row % LL;
    int tok = x_enc[row];
    float2 e  = ((const float2*)(emb + (size_t)tok * DD))[lane];
    float2 p1 = ((const float2*)(pos1 + (l / 25) * DD))[lane];
    float2 p2 = ((const float2*)(pos2 + (l % 25) * DD))[lane];
    float2 v = make_float2(e.x + p1.x + p2.x, e.y + p1.y + p2.y);
    ((float2*)(x1 + (size_t)row * DD))[lane] = v;
    ((float2*)(x2 + (size_t)row * DD))[lane] = v;
    float2 gg = ((const float2*)g)[lane];
    float2 bb = ((const float2*)b)[lane];
    float s = v.x + v.y;
    float sq = v.x * v.x + v.y * v.y;
    #pragma unroll
    for (int off = 32; off > 0; off >>= 1) {
        s += __shfl_down(s, off, 64);
        sq += __shfl_down(sq, off, 64);
    }
    s = __shfl(s, 0, 64);
    sq = __shfl(sq, 0, 64);
    float mean = s * (1.0f / DD);
    float var = sq * (1.0f / DD) - mean * mean;
    float rstd = rsqrtf(var + 1e-5f);
    __hip_bfloat16* yp = y + (size_t)row * DD + lane * 2;
    yp[0] = __float2bfloat16((v.x - mean) * rstd * gg.x + bb.x);
    yp[1] = __float2bfloat16((v.y - mean) * rstd * gg.y + bb.y);
}

// ---------------- weight cast + transpose ----------------
__device__ __forceinline__ void castT_body(
    const float* __restrict__ s, __hip_bfloat16* __restrict__ d,
    int K, int N, int kb, int nb)
{
    __shared__ float tile[32][33];
    int tx = threadIdx.x & 31, ty = threadIdx.x >> 5;
    #pragma unroll
    for (int r = 0; r < 32; r += 8)
        tile[r + ty][tx] = s[(size_t)(kb + r + ty) * N + nb + tx];
    __syncthreads();
    #pragma unroll
    for (int r = 0; r < 32; r += 8)
        d[(size_t)(nb + r + ty) * K + kb + tx] = __float2bfloat16(tile[tx][r + ty]);
}

__global__ __launch_bounds__(256) void cast_all_kernel(
    const float* __restrict__ Wqk, const float* __restrict__ Wv,
    const float* __restrict__ Wo,  const float* __restrict__ W1,
    const float* __restrict__ W2,
    __hip_bfloat16* __restrict__ dqk, __hip_bfloat16* __restrict__ dv,
    __hip_bfloat16* __restrict__ dwo, __hip_bfloat16* __restrict__ d1,
    __hip_bfloat16* __restrict__ d2)
{
    int z = blockIdx.x;
    if (z < 288) {
        int m = z >> 4, t = z & 15;
        int which = m / 6, dd = m % 6;
        const float* s = (which == 0 ? Wqk : (which == 1 ? Wv : Wo)) + (size_t)dd * 16384;
        __hip_bfloat16* d = (which == 0 ? dqk : (which == 1 ? dv : dwo))
                            + (size_t)dd * (which == 2 ? 16384 : 32768);
        castT_body(s, d, 128, 128, (t >> 2) * 32, (t & 3) * 32);
    } else if (z < 672) {
        int i = z - 288; int dd = i >> 6; int t = i & 63;
        castT_body(W1 + (size_t)dd * 65536, d1 + (size_t)dd * 65536,
                   128, 512, (t >> 4) * 32, (t & 15) * 32);
    } else {
        int i = z - 672; int dd = i >> 6; int t = i & 63;
        castT_body(W2 + (size_t)dd * 65536, d2 + (size_t)dd * 65536,
                   512, 128, (t >> 2) * 32, (t & 3) * 32);
    }
}

__global__ __launch_bounds__(256) void castWp_kernel(
    const float* __restrict__ src, __hip_bfloat16* __restrict__ dst)
{
    castT_body(src, dst, KP, 128, blockIdx.x * 32, blockIdx.y * 32);
}

// ---------------- bf16 MFMA GEMM (plain; layer-0 qkv) ----------------
template<int K, int N>
__global__ __launch_bounds__(256) void gemm_qkv_kernel(
    const __hip_bfloat16* __restrict__ A, const __hip_bfloat16* __restrict__ Bt,
    __hip_bfloat16* __restrict__ Cdst)
{
    __shared__ unsigned short As[64 * 128];
    __shared__ unsigned short Bs[128 * 128];
    int tid = threadIdx.x;
    int l = tid & 63, w = tid >> 6;
    int wr = w >> 1, wc = w & 1;
    int lr = l & 15, q = l >> 4;
    int m0 = blockIdx.y * 64;
    int n0 = blockIdx.x * 128;

    f32x4 acc[2][4];
    #pragma unroll
    for (int mt = 0; mt < 2; ++mt)
        #pragma unroll
        for (int nt = 0; nt < 4; ++nt) acc[mt][nt] = (f32x4){0.f, 0.f, 0.f, 0.f};

    for (int kt = 0; kt < K; kt += 128) {
        if (kt) __syncthreads();
        #pragma unroll
        for (int p = 0; p < 4; ++p) {
            int n = p * 256 + tid;
            int r = n >> 4;
            int c = (n & 15) ^ (r & 7);
            *(uint4*)&As[n * 8] = *(const uint4*)(A + (size_t)(m0 + r) * K + kt + c * 8);
        }
        #pragma unroll
        for (int p = 0; p < 8; ++p) {
            int n = p * 256 + tid;
            int r = n >> 4;
            int c = (n & 15) ^ (r & 7);
            *(uint4*)&Bs[n * 8] = *(const uint4*)(Bt + (size_t)(n0 + r) * K + kt + c * 8);
        }
        __syncthreads();
        #pragma unroll
        for (int kk = 0; kk < 4; ++kk) {
            bf16x8 afr[2], bfr[4];
            #pragma unroll
            for (int mt = 0; mt < 2; ++mt) {
                int rA = wr * 32 + mt * 16 + lr;
                int cc = (kk * 4 + q) ^ (rA & 7);
                afr[mt] = *(const bf16x8*)&As[(rA * 16 + cc) * 8];
            }
            #pragma unroll
            for (int nt = 0; nt < 4; ++nt) {
                int rB = wc * 64 + nt * 16 + lr;
                int cc = (kk * 4 + q) ^ (rB & 7);
                bfr[nt] = *(const bf16x8*)&Bs[(rB * 16 + cc) * 8];
            }
            #pragma unroll
            for (int mt = 0; mt < 2; ++mt)
                #pragma unroll
                for (int nt = 0; nt < 4; ++nt)
                    acc[mt][nt] = __builtin_amdgcn_mfma_f32_16x16x32_bf16(
                        afr[mt], bfr[nt], acc[mt][nt], 0, 0, 0);
        }
    }

    #pragma unroll
    for (int mt = 0; mt < 2; ++mt)
        #pragma unroll
        for (int nt = 0; nt < 4; ++nt) {
            int col = n0 + wc * 64 + nt * 16 + lr;
            #pragma unroll
            for (int r = 0; r < 4; ++r) {
                int row = m0 + wr * 32 + mt * 16 + q * 4 + r;
                Cdst[(size_t)row * N + col] = __float2bfloat16(acc[mt][nt][r]);
            }
        }
}

// ---------------- attention: MFMA flash-style, S^T, 2 blocks per (b,h) (r16-verified) ----------------
__global__ __launch_bounds__(256) void attn_kernel(
    const __hip_bfloat16* __restrict__ qkv, __hip_bfloat16* __restrict__ o)
{
    int z  = blockIdx.x >> 9;
    int bh = blockIdx.x & 511;
    int b = bh >> 3, hh = bh & 7;
    const unsigned short* base = (const unsigned short*)qkv + (size_t)b * LL * 256 + hh * DHH;

    __shared__ unsigned short knb[LL + 2][24];
    __shared__ unsigned short vtb[16][LL + 24];
    __shared__ float cq[LL];
    __shared__ unsigned short ptile[4][16][40];

    int t = threadIdx.x;
    for (int r = t; r < LL; r += 256) {
        const unsigned short* qp = base + (size_t)r * 256;
        unsigned short qs[16], vs16[16];
        *(uint4*)&qs[0]  = *(const uint4*)(qp);
        *(uint4*)&qs[8]  = *(const uint4*)(qp + 8);
        *(uint4*)&vs16[0] = *(const uint4*)(qp + 128);
        *(uint4*)&vs16[8] = *(const uint4*)(qp + 136);
        float q[16];
        #pragma unroll
        for (int d = 0; d < 16; ++d) q[d] = bs2f(qs[d]);
        float nrm = 0.f;
        #pragma unroll
        for (int d = 0; d < 16; ++d) nrm = fmaf(q[d], q[d], nrm);
        float qn = sqrtf(nrm);
        float inv = 1.0f / fmaxf(qn, 1e-12f);
        cq[r] = 0.25f * qn;
        unsigned short kb[16];
        #pragma unroll
        for (int d = 0; d < 16; ++d) kb[d] = f2bs(q[d] * inv);
        *(uint4*)&knb[r][0] = *(uint4*)&kb[0];
        *(uint4*)&knb[r][8] = *(uint4*)&kb[8];
        *(uint4*)&knb[r][16] = make_uint4(0u, 0u, 0u, 0u);
        #pragma unroll
        for (int d = 0; d < 16; ++d) vtb[d][r] = vs16[d];
    }
    if (t < 16) {
        #pragma unroll
        for (int c = 0; c < 24; ++c) vtb[t][LL + c] = 0;
    }
    if (t < 2) {
        #pragma unroll
        for (int c = 0; c < 24; ++c) knb[LL + t][c] = 0;
    }

    int w = t >> 6, l = t & 63;
    int lr = l & 15, q4 = l >> 4;
    __syncthreads();

    bf16x8 zfrag = {0, 0, 0, 0, 0, 0, 0, 0};
    bf16x8 onesf;
    #pragma unroll
    for (int i = 0; i < 8; ++i) onesf[i] = (short)0x3F80;

    int slot = 2 * w + z;
    int strips[3] = { slot, 15 - slot, 16 + slot };
    #pragma unroll
    for (int si = 0; si < 3; ++si) {
        int s = strips[si];
        int r0 = s * 16;
        bf16x8 bq = *(const bf16x8*)&knb[r0 + lr][q4 * 8];
        float ccq = cq[r0 + lr];
        int qg = r0 + lr;

        f32x4 oacc = (f32x4){0.f, 0.f, 0.f, 0.f};
        f32x4 lacc = (f32x4){0.f, 0.f, 0.f, 0.f};

        for (int jt = 0; jt <= s; jt += 2) {
            bf16x8 a0 = *(const bf16x8*)&knb[jt * 16 + lr][(q4 & 1) * 8];
            a0 = (q4 < 2) ? a0 : zfrag;
            bf16x8 a1 = *(const bf16x8*)&knb[(jt + 1) * 16 + lr][(q4 & 1) * 8];
            a1 = (q4 < 2) ? a1 : zfrag;
            f32x4 s0 = __builtin_amdgcn_mfma_f32_16x16x32_bf16(
                a0, bq, (f32x4){0.f, 0.f, 0.f, 0.f}, 0, 0, 0);
            f32x4 s1 = __builtin_amdgcn_mfma_f32_16x16x32_bf16(
                a1, bq, (f32x4){0.f, 0.f, 0.f, 0.f}, 0, 0, 0);

            unsigned int pk0[2], pk1[2];
            #pragma unroll
            for (int h = 0; h < 2; ++h) {
                int ja = jt * 16 + q4 * 4 + 2 * h;
                float pa = __expf(fmaf(s0[2 * h],     ccq, -ccq));
                pa = (ja < qg) ? pa : 0.f;
                float pb = __expf(fmaf(s0[2 * h + 1], ccq, -ccq));
                pb = (ja + 1 < qg) ? pb : 0.f;
                pk0[h] = (unsigned int)f2bs(pa) | ((unsigned int)f2bs(pb) << 16);
                float pc = __expf(fmaf(s1[2 * h],     ccq, -ccq));
                pc = (ja + 16 < qg) ? pc : 0.f;
                float pd = __expf(fmaf(s1[2 * h + 1], ccq, -ccq));
                pd = (ja + 17 < qg) ? pd : 0.f;
                pk1[h] = (unsigned int)f2bs(pc) | ((unsigned int)f2bs(pd) << 16);
            }
            *(uint2*)&ptile[w][lr][q4 * 4]      = make_uint2(pk0[0], pk0[1]);
            *(uint2*)&ptile[w][lr][16 + q4 * 4] = make_uint2(pk1[0], pk1[1]);
            asm volatile("s_waitcnt lgkmcnt(0)" ::: "memory");
            bf16x8 pfrag = *(const bf16x8*)&ptile[w][lr][q4 * 8];
            bf16x8 vfrag = *(const bf16x8*)&vtb[lr][jt * 16 + q4 * 8];
            oacc = __builtin_amdgcn_mfma_f32_16x16x32_bf16(pfrag, vfrag, oacc, 0, 0, 0);
            lacc = __builtin_amdgcn_mfma_f32_16x16x32_bf16(pfrag, onesf, lacc, 0, 0, 0);
        }

        if (s == 0 && q4 == 0) {
            lacc[0] = 1.0f;
            oacc[0] = bs2f(vtb[lr][0]);
        }
        unsigned short* ob = (unsigned short*)o + (size_t)(b * LL + r0) * DD + hh * 16 + lr;
        #pragma unroll
        for (int reg = 0; reg < 4; ++reg) {
            float ov = oacc[reg] / lacc[reg];
            ob[(size_t)(q4 * 4 + reg) * DD] = f2bs(ov);
        }
    }
}

// ---------------- mega_wolf (BM=32): x1 += o@Wo + bo ; h=LN2 in As ; hff = gelu(h@W1+b1) ----------------
__global__ __launch_bounds__(256) void mega_wolf_kernel(
    const __hip_bfloat16* __restrict__ Ao, const __hip_bfloat16* __restrict__ WoTd,
    const float* __restrict__ bod, float* __restrict__ x1,
    const float* __restrict__ lng, const float* __restrict__ lnb,
    const __hip_bfloat16* __restrict__ W1Td, const float* __restrict__ b1d,
    __hip_bfloat16* __restrict__ hff)
{
    __shared__ unsigned short As[32 * 128];
    __shared__ unsigned short Bs[128 * 128];
    int tid = threadIdx.x;
    int l = tid & 63, w = tid >> 6;
    int lr = l & 15, q = l >> 4;
    int m0 = blockIdx.x * 32;

    f32x4 acc[2][2];
    #pragma unroll
    for (int mt = 0; mt < 2; ++mt)
        #pragma unroll
        for (int nt = 0; nt < 2; ++nt) acc[mt][nt] = (f32x4){0.f, 0.f, 0.f, 0.f};

    #pragma unroll
    for (int p = 0; p < 2; ++p) {
        int n = p * 256 + tid;
        int r = n >> 4;
        int c = (n & 15) ^ (r & 7);
        *(uint4*)&As[n * 8] = *(const uint4*)(Ao + (size_t)(m0 + r) * 128 + c * 8);
    }
    #pragma unroll
    for (int p = 0; p < 8; ++p) {
        int n = p * 256 + tid;
        int r = n >> 4;
        int c = (n & 15) ^ (r & 7);
        *(uint4*)&Bs[n * 8] = *(const uint4*)(WoTd + (size_t)r * 128 + c * 8);
    }
    __syncthreads();
    #pragma unroll
    for (int kk = 0; kk < 4; ++kk) {
        bf16x8 afr[2], bfr[2];
        #pragma unroll
        for (int mt = 0; mt < 2; ++mt) {
            int rA = mt * 16 + lr;
            int cc = (kk * 4 + q) ^ (rA & 7);
            afr[mt] = *(const bf16x8*)&As[(rA * 16 + cc) * 8];
        }
        #pragma unroll
        for (int nt = 0; nt < 2; ++nt) {
            int rB = w * 32 + nt * 16 + lr;
            int cc = (kk * 4 + q) ^ (rB & 7);
            bfr[nt] = *(const bf16x8*)&Bs[(rB * 16 + cc) * 8];
        }
        #pragma unroll
        for (int mt = 0; mt < 2; ++mt)
            #pragma unroll
            for (int nt = 0; nt < 2; ++nt)
                acc[mt][nt] = __builtin_amdgcn_mfma_f32_16x16x32_bf16(
                    afr[mt], bfr[nt], acc[mt][nt], 0, 0, 0);
    }

    float* fp = (float*)Bs;
    __syncthreads();
    #pragma unroll
    for (int mt = 0; mt < 2; ++mt)
        #pragma unroll
        for (int nt = 0; nt < 2; ++nt) {
            int col = w * 32 + nt * 16 + lr;
            float bv = bod[col];
            #pragma unroll
            for (int r = 0; r < 4; ++r) {
                int rowL = mt * 16 + q * 4 + r;
                fp[rowL * 128 + col] = acc[mt][nt][r] + bv
                                       + x1[(size_t)(m0 + rowL) * 128 + col];
            }
        }
    __syncthreads();
    {
        int rl = tid >> 3, sub = tid & 7;
        float s = 0.f, sq = 0.f;
        #pragma unroll
        for (int c4 = 0; c4 < 4; ++c4) {
            float4 v = *(const float4*)&fp[rl * 128 + sub * 16 + c4 * 4];
            s  += (v.x + v.y) + (v.z + v.w);
            sq += (v.x * v.x + v.y * v.y) + (v.z * v.z + v.w * v.w);
        }
        s  += __shfl_xor(s, 1);  s  += __shfl_xor(s, 2);  s  += __shfl_xor(s, 4);
        sq += __shfl_xor(sq, 1); sq += __shfl_xor(sq, 2); sq += __shfl_xor(sq, 4);
        float mean = s * (1.0f / 128.0f);
        float var  = sq * (1.0f / 128.0f) - mean * mean;
        float rstd = rsqrtf(var + 1e-5f);
        #pragma unroll
        for (int c4 = 0; c4 < 4; ++c4) {
            int col = sub * 16 + c4 * 4;
            float4 v  = *(const float4*)&fp[rl * 128 + col];
            *(float4*)(x1 + (size_t)(m0 + rl) * 128 + col) = v;
            float4 g4 = *(const float4*)(lng + col);
            float4 b4 = *(const float4*)(lnb + col);
            unsigned short pk[4];
            pk[0] = f2bs((v.x - mean) * rstd * g4.x + b4.x);
            pk[1] = f2bs((v.y - mean) * rstd * g4.y + b4.y);
            pk[2] = f2bs((v.z - mean) * rstd * g4.z + b4.z);
            pk[3] = f2bs((v.w - mean) * rstd * g4.w + b4.w);
            int addr = rl * 128 + (((col >> 3) ^ (rl & 7)) << 3) + (col & 7);
            *(ushort4*)&As[addr] = *(ushort4*)&pk[0];
        }
    }
    __syncthreads();

    for (int nc = 0; nc < 4; ++nc) {
        if (nc) __syncthreads();
        #pragma unroll
        for (int p = 0; p < 8; ++p) {
            int n = p * 256 + tid;
            int r = n >> 4;
            int c = (n & 15) ^ (r & 7);
            *(uint4*)&Bs[n * 8] = *(const uint4*)(W1Td + (size_t)(nc * 128 + r) * 128 + c * 8);
        }
        __syncthreads();
        f32x4 a2[2][2];
        #pragma unroll
        for (int mt = 0; mt < 2; ++mt)
            #pragma unroll
            for (int nt = 0; nt < 2; ++nt) a2[mt][nt] = (f32x4){0.f, 0.f, 0.f, 0.f};
        #pragma unroll
        for (int kk = 0; kk < 4; ++kk) {
            bf16x8 afr[2], bfr[2];
            #pragma unroll
            for (int mt = 0; mt < 2; ++mt) {
                int rA = mt * 16 + lr;
                int cc = (kk * 4 + q) ^ (rA & 7);
                afr[mt] = *(const bf16x8*)&As[(rA * 16 + cc) * 8];
            }
            #pragma unroll
            for (int nt = 0; nt < 2; ++nt) {
                int rB = w * 32 + nt * 16 + lr;
                int cc = (kk * 4 + q) ^ (rB & 7);
                bfr[nt] = *(const bf16x8*)&Bs[(rB * 16 + cc) * 8];
            }
            #pragma unroll
            for (int mt = 0; mt < 2; ++mt)
                #pragma unroll
                for (int nt = 0; nt < 2; ++nt)
                    a2[mt][nt] = __builtin_amdgcn_mfma_f32_16x16x32_bf16(
                        afr[mt], bfr[nt], a2[mt][nt], 0, 0, 0);
        }
        #pragma unroll
        for (int mt = 0; mt < 2; ++mt)
            #pragma unroll
            for (int nt = 0; nt < 2; ++nt) {
                int colg = nc * 128 + w * 32 + nt * 16 + lr;
                float bv = b1d[colg];
                #pragma unroll
                for (int r = 0; r < 4; ++r) {
                    int row = m0 + mt * 16 + q * 4 + r;
                    hff[(size_t)row * 512 + colg] =
                        __float2bfloat16(gelu_exact(a2[mt][nt][r] + bv));
                }
            }
    }
}

// ---------------- mega_ffq (BM=32): x2 += hff@W2+b2 ; h=LN1' in As ; qkv = h@WqvT ----------------
template<bool LAST>
__global__ __launch_bounds__(256) void mega_ffq_kernel(
    const __hip_bfloat16* __restrict__ Ahff, const __hip_bfloat16* __restrict__ W2Td,
    const float* __restrict__ b2d, float* __restrict__ x2,
    const float* __restrict__ x1,
    const float* __restrict__ lng, const float* __restrict__ lnb,
    const __hip_bfloat16* __restrict__ WqvTd, __hip_bfloat16* __restrict__ qkv,
    __hip_bfloat16* __restrict__ hout)
{
    __shared__ unsigned short As[32 * 128];
    __shared__ unsigned short Bs[128 * 128];
    int tid = threadIdx.x;
    int l = tid & 63, w = tid >> 6;
    int lr = l & 15, q = l >> 4;
    int m0 = blockIdx.x * 32;

    f32x4 acc[2][2];
    #pragma unroll
    for (int mt = 0; mt < 2; ++mt)
        #pragma unroll
        for (int nt = 0; nt < 2; ++nt) acc[mt][nt] = (f32x4){0.f, 0.f, 0.f, 0.f};

    for (int kt = 0; kt < 512; kt += 128) {
        if (kt) __syncthreads();
        #pragma unroll
        for (int p = 0; p < 2; ++p) {
            int n = p * 256 + tid;
            int r = n >> 4;
            int c = (n & 15) ^ (r & 7);
            *(uint4*)&As[n * 8] = *(const uint4*)(Ahff + (size_t)(m0 + r) * 512 + kt + c * 8);
        }
        #pragma unroll
        for (int p = 0; p < 8; ++p) {
            int n = p * 256 + tid;
            int r = n >> 4;
            int c = (n & 15) ^ (r & 7);
            *(uint4*)&Bs[n * 8] = *(const uint4*)(W2Td + (size_t)r * 512 + kt + c * 8);
        }
        __syncthreads();
        #pragma unroll
        for (int kk = 0; kk < 4; ++kk) {
            bf16x8 afr[2], bfr[2];
            #pragma unroll
            for (int mt = 0; mt < 2; ++mt) {
                int rA = mt * 16 + lr;
                int cc = (kk * 4 + q) ^ (rA & 7);
                afr[mt] = *(const bf16x8*)&As[(rA * 16 + cc) * 8];
            }
            #pragma unroll
            for (int nt = 0; nt < 2; ++nt) {
                int rB = w * 32 + nt * 16 + lr;
                int cc = (kk * 4 + q) ^ (rB & 7);
                bfr[nt] = *(const bf16x8*)&Bs[(rB * 16 + cc) * 8];
            }
            #pragma unroll
            for (int mt = 0; mt < 2; ++mt)
                #pragma unroll
                for (int nt = 0; nt < 2; ++nt)
                    acc[mt][nt] = __builtin_amdgcn_mfma_f32_16x16x32_bf16(
                        afr[mt], bfr[nt], acc[mt][nt], 0, 0, 0);
        }
    }

    float* fp = (float*)Bs;
    __syncthreads();
    #pragma unroll
    for (int mt = 0; mt < 2; ++mt)
        #pragma unroll
        for (int nt = 0; nt < 2; ++nt) {
            int col = w * 32 + nt * 16 + lr;
            float bv = b2d[col];
            #pragma unroll
            for (int r = 0; r < 4; ++r) {
                int rowL = mt * 16 + q * 4 + r;
                fp[rowL * 128 + col] = acc[mt][nt][r] + bv
                                       + x2[(size_t)(m0 + rowL) * 128 + col];
            }
        }
    __syncthreads();
    {
        int rl = tid >> 3, sub = tid & 7;
        float s = 0.f, sq = 0.f;
        #pragma unroll
        for (int c4 = 0; c4 < 4; ++c4) {
            float4 v = *(const float4*)&fp[rl * 128 + sub * 16 + c4 * 4];
            if (LAST) {
                float4 xo = *(const float4*)(x1 + (size_t)(m0 + rl) * 128 + sub * 16 + c4 * 4);
                v.x = (v.x + xo.x) * 0.5f; v.y = (v.y + xo.y) * 0.5f;
                v.z = (v.z + xo.z) * 0.5f; v.w = (v.w + xo.w) * 0.5f;
            }
            s  += (v.x + v.y) + (v.z + v.w);
            sq += (v.x * v.x + v.y * v.y) + (v.z * v.z + v.w * v.w);
        }
        s  += __shfl_xor(s, 1);  s  += __shfl_xor(s, 2);  s  += __shfl_xor(s, 4);
        sq += __shfl_xor(sq, 1); sq += __shfl_xor(sq, 2); sq += __shfl_xor(sq, 4);
        float mean = s * (1.0f / 128.0f);
        float var  = sq * (1.0f / 128.0f) - mean * mean;
        float rstd = rsqrtf(var + 1e-5f);
        #pragma unroll
        for (int c4 = 0; c4 < 4; ++c4) {
            int col = sub * 16 + c4 * 4;
            float4 v = *(const float4*)&fp[rl * 128 + col];
            if (LAST) {
                float4 xo = *(const float4*)(x1 + (size_t)(m0 + rl) * 128 + col);
                v.x = (v.x + xo.x) * 0.5f; v.y = (v.y + xo.y) * 0.5f;
                v.z = (v.z + xo.z) * 0.5f; v.w = (v.w + xo.w) * 0.5f;
            } else {
                *(float4*)(x2 + (size_t)(m0 + rl) * 128 + col) = v;
            }
            float4 g4 = *(const float4*)(lng + col);
            float4 b4 = *(const float4*)(lnb + col);
            unsigned short pk[4];
            pk[0] = f2bs((v.x - mean) * rstd * g4.x + b4.x);
            pk[1] = f2bs((v.y - mean) * rstd * g4.y + b4.y);
            pk[2] = f2bs((v.z - mean) * rstd * g4.z + b4.z);
            pk[3] = f2bs((v.w - mean) * rstd * g4.w + b4.w);
            if (LAST) {
                *(ushort4*)((unsigned short*)hout + (size_t)(m0 + rl) * 128 + col)
                    = *(ushort4*)&pk[0];
            } else {
                int addr = rl * 128 + (((col >> 3) ^ (rl & 7)) << 3) + (col & 7);
                *(ushort4*)&As[addr] = *(ushort4*)&pk[0];
            }
        }
    }
    __syncthreads();

    if (!LAST) {
        for (int nc = 0; nc < 2; ++nc) {
            if (nc) __syncthreads();
            #pragma unroll
            for (int p = 0; p < 8; ++p) {
                int n = p * 256 + tid;
                int r = n >> 4;
                int c = (n & 15) ^ (r & 7);
                *(uint4*)&Bs[n * 8] = *(const uint4*)(WqvTd + (size_t)(nc * 128 + r) * 128 + c * 8);
            }
            __syncthreads();
            f32x4 a2[2][2];
            #pragma unroll
            for (int mt = 0; mt < 2; ++mt)
                #pragma unroll
                for (int nt = 0; nt < 2; ++nt) a2[mt][nt] = (f32x4){0.f, 0.f, 0.f, 0.f};
            #pragma unroll
            for (int kk = 0; kk < 4; ++kk) {
                bf16x8 afr[2], bfr[2];
                #pragma unroll
                for (int mt = 0; mt < 2; ++mt) {
                    int rA = mt * 16 + lr;
                    int cc = (kk * 4 + q) ^ (rA & 7);
                    afr[mt] = *(const bf16x8*)&As[(rA * 16 + cc) * 8];
                }
                #pragma unroll
                for (int nt = 0; nt < 2; ++nt) {
                    int rB = w * 32 + nt * 16 + lr;
                    int cc = (kk * 4 + q) ^ (rB & 7);
                    bfr[nt] = *(const bf16x8*)&Bs[(rB * 16 + cc) * 8];
                }
                #pragma unroll
                for (int mt = 0; mt < 2; ++mt)
                    #pragma unroll
                    for (int nt = 0; nt < 2; ++nt)
                        a2[mt][nt] = __builtin_amdgcn_mfma_f32_16x16x32_bf16(
                            afr[mt], bfr[nt], a2[mt][nt], 0, 0, 0);
            }
            #pragma unroll
            for (int mt = 0; mt < 2; ++mt)
                #pragma unroll
                for (int nt = 0; nt < 2; ++nt) {
                    int colg = nc * 128 + w * 32 + nt * 16 + lr;
                    #pragma unroll
                    for (int r = 0; r < 4; ++r) {
                        int row = m0 + mt * 16 + q * 4 + r;
                        qkv[(size_t)row * 256 + colg] = __float2bfloat16(a2[mt][nt][r]);
                    }
                }
        }
    }
}

// ---------------- final projection: MFMA split-K + reduce ----------------
__global__ __launch_bounds__(256) void final_mfma_kernel(
    const __hip_bfloat16* __restrict__ A, const __hip_bfloat16* __restrict__ Bt,
    float* __restrict__ partials)
{
    __shared__ unsigned short As[64 * 128];
    __shared__ unsigned short Bs[128 * 128];
    int tid = threadIdx.x;
    int l = tid & 63, w = tid >> 6;
    int wr = w >> 1, wc = w & 1;
    int lr = l & 15, q = l >> 4;
    int kbase = blockIdx.x * KCHUNK;

    f32x4 acc[2][4];
    #pragma unroll
    for (int mt = 0; mt < 2; ++mt)
        #pragma unroll
        for (int nt = 0; nt < 4; ++nt) acc[mt][nt] = (f32x4){0.f, 0.f, 0.f, 0.f};

    for (int kt = 0; kt < KCHUNK; kt += 128) {
        if (kt) __syncthreads();
        #pragma unroll
        for (int p = 0; p < 4; ++p) {
            int n = p * 256 + tid;
            int r = n >> 4;
            int c = (n & 15) ^ (r & 7);
            *(uint4*)&As[n * 8] = *(const uint4*)(A + (size_t)r * KP + kbase + kt + c * 8);
        }
        #pragma unroll
        for (int p = 0; p < 8; ++p) {
            int n = p * 256 + tid;
            int r = n >> 4;
            int c = (n & 15) ^ (r & 7);
            *(uint4*)&Bs[n * 8] = *(const uint4*)(Bt + (size_t)r * KP + kbase + kt + c * 8);
        }
        __syncthreads();
        #pragma unroll
        for (int kk = 0; kk < 4; ++kk) {
            bf16x8 afr[2], bfr[4];
            #pragma unroll
            for (int mt = 0; mt < 2; ++mt) {
                int rA = wr * 32 + mt * 16 + lr;
                int cc = (kk * 4 + q) ^ (rA & 7);
                afr[mt] = *(const bf16x8*)&As[(rA * 16 + cc) * 8];
            }
            #pragma unroll
            for (int nt = 0; nt < 4; ++nt) {
                int rB = wc * 64 + nt * 16 + lr;
                int cc = (kk * 4 + q) ^ (rB & 7);
                bfr[nt] = *(const bf16x8*)&Bs[(rB * 16 + cc) * 8];
            }
            #pragma unroll
            for (int mt = 0; mt < 2; ++mt)
                #pragma unroll
                for (int nt = 0; nt < 4; ++nt)
                    acc[mt][nt] = __builtin_amdgcn_mfma_f32_16x16x32_bf16(
                        afr[mt], bfr[nt], acc[mt][nt], 0, 0, 0);
        }
    }

    float* dst = partials + (size_t)blockIdx.x * (64 * 128);
    #pragma unroll
    for (int mt = 0; mt < 2; ++mt)
        #pragma unroll
        for (int nt = 0; nt < 4; ++nt) {
            int col = wc * 64 + nt * 16 + lr;
            #pragma unroll
            for (int r = 0; r < 4; ++r) {
                int row = wr * 32 + mt * 16 + q * 4 + r;
                dst[row * 128 + col] = acc[mt][nt][r];
            }
        }
}

__global__ __launch_bounds__(256) void final_reduce_kernel(
    const float* __restrict__ partials, const float* __restrict__ bp,
    float* __restrict__ out)
{
    int j = blockIdx.x * 256 + threadIdx.x;
    float s = bp[j & (COUT - 1)];
    #pragma unroll 8
    for (int p = 0; p < KSPLIT; ++p)
        s += partials[(size_t)p * 8192 + j];
    out[j] = s;
}

// ---------------- launch ----------------
extern "C" void kernel_launch(void* const* d_in, const int* in_sizes, int n_in,
                              void* d_out, int out_size, void* d_ws, size_t ws_size,
                              hipStream_t stream)
{
    const int*   x_enc = (const int*)  d_in[0];
    const float* emb   = (const float*)d_in[1];
    const float* pos1  = (const float*)d_in[2];
    const float* pos2  = (const float*)d_in[3];
    const float* ln1_g = (const float*)d_in[4];
    const float* ln1_b = (const float*)d_in[5];
    const float* Wqk   = (const float*)d_in[6];
    const float* Wv    = (const float*)d_in[7];
    const float* Wo    = (const float*)d_in[8];
    const float* bo    = (const float*)d_in[9];
    const float* ln2_g = (const float*)d_in[10];
    const float* ln2_b = (const float*)d_in[11];
    const float* W1    = (const float*)d_in[12];
    const float* b1    = (const float*)d_in[13];
    const float* W2    = (const float*)d_in[14];
    const float* b2    = (const float*)d_in[15];
    const float* lnf_g = (const float*)d_in[16];
    const float* lnf_b = (const float*)d_in[17];
    const float* Wp    = (const float*)d_in[18];
    const float* bp    = (const float*)d_in[19];
    float* out = (float*)d_out;

    const size_t SZ = (size_t)MROWS * DD;
    float* ws_f = (float*)d_ws;
    float* x1 = ws_f;                                        // fp32 [M,128]
    float* x2 = ws_f + SZ;                                   // fp32 [M,128]
    __hip_bfloat16* hff  = (__hip_bfloat16*)(ws_f + 2 * SZ); // bf16 [M,512] (2*SZ floats)
    __hip_bfloat16* h_bf = (__hip_bfloat16*)(ws_f + 4 * SZ); // bf16 [M,128]
    __hip_bfloat16* o_bf = h_bf + SZ;                        // bf16 [M,128]
    __hip_bfloat16* wqvT = o_bf + SZ;                        // 6*[256,128]
    __hip_bfloat16* woT  = wqvT + 6 * 32768;                 // 6*[128,128]
    __hip_bfloat16* w1T  = woT  + 6 * 16384;                 // 6*[512,128]
    __hip_bfloat16* w2T  = w1T  + 6 * 65536;                 // 6*[128,512]
    __hip_bfloat16* WpT  = w2T  + 6 * 65536;                 // [128,49152] bf16
    __hip_bfloat16* qkv  = WpT;                              // [M,256] bf16 — ALIASES WpT
    float* partials = (float*)(WpT + (size_t)COUT * KP);     // [96][8192] fp32

    cast_all_kernel<<<dim3(1056), dim3(256), 0, stream>>>(
        Wqk, Wv, Wo, W1, W2, wqvT, wqvT + 16384, woT, w1T, w2T);
    embedln_kernel<<<dim3(MROWS / 4), dim3(256), 0, stream>>>(
        x_enc, emb, pos1, pos2, ln1_g, ln1_b, x1, x2, h_bf);
    gemm_qkv_kernel<128, 256><<<dim3(2, MROWS / 64), dim3(256), 0, stream>>>(
        h_bf, wqvT, qkv);

    for (int d = 0; d < DEPTH; ++d) {
        attn_kernel<<<dim3(BB * HH * 2), dim3(256), 0, stream>>>(qkv, o_bf);
        mega_wolf_kernel<<<dim3(MROWS / 32), dim3(256), 0, stream>>>(
            o_bf, woT + (size_t)d * 16384, bo + d * DD, x1,
            ln2_g + d * DD, ln2_b + d * DD,
            w1T + (size_t)d * 65536, b1 + d * FFD, hff);
        if (d < DEPTH - 1) {
            mega_ffq_kernel<false><<<dim3(MROWS / 32), dim3(256), 0, stream>>>(
                hff, w2T + (size_t)d * 65536, b2 + d * DD, x2, nullptr,
                ln1_g + (d + 1) * DD, ln1_b + (d + 1) * DD,
                wqvT + (size_t)(d + 1) * 32768, qkv, nullptr);
        } else {
            mega_ffq_kernel<true><<<dim3(MROWS / 32), dim3(256), 0, stream>>>(
                hff, w2T + (size_t)d * 65536, b2 + d * DD, x2, x1,
                lnf_g, lnf_b, nullptr, nullptr, h_bf);
        }
    }

    castWp_kernel<<<dim3(KP / 32, 4), dim3(256), 0, stream>>>(Wp, WpT);
    final_mfma_kernel<<<dim3(KSPLIT), dim3(256), 0, stream>>>(h_bf, WpT, partials);
    final_reduce_kernel<<<dim3(32), dim3(256), 0, stream>>>(partials, bp, out);
}